// Round 1
// baseline (448.550 us; speedup 1.0000x reference)
//
#include <hip/hip_runtime.h>

// Blur_1803886264378: depthwise 4x4 upfirdn2d blur, fp32.
// B=8, C=128, H=W=256, pad=(2,1) both dims -> same-size output.
// Separable (rank-1 [1,3,3,1] x [1,3,3,1]) blur fused in one kernel.
//
// R3 changes vs R2:
//  - Pair-row software pipeline: two independent global_load_dwordx4 issued
//    back-to-back per loop iteration (2x memory-level parallelism per wave),
//    half the loop iterations.
//  - Nontemporal output stores: the 256 MiB write stream is never re-read;
//    keep it from evicting input halo rows from L2.
//  - ldrow/hblur split: OOB rows skip only the load; zeros flow through the
//    shuffles, so the hot loop has just one wave-uniform branch per load.

#define BB 8
#define CC 128
#define HH 256
#define WW 256
#define RPW 16   // rows per wave

typedef float f32x4 __attribute__((ext_vector_type(4)));

__global__ __launch_bounds__(256) void blur_kernel(
    const float* __restrict__ x, const float* __restrict__ kern,
    float* __restrict__ out)
{
    const int lane  = threadIdx.x & 63;
    const int wv    = threadIdx.x >> 6;
    const int strip = blockIdx.x & 3;       // 4 block-strips of 64 rows
    const int bc    = blockIdx.x >> 2;

    const int row0 = strip * 64 + wv * RPW; // first output row for this wave
    const int col0 = lane * 4;              // first output col for this lane

    // Flipped kernel: w[di][dj] = kern[(3-di)*4 + (3-dj)].
    // Rank-1: v[dj] = w[0][dj], u[di] = w[di][0]/w[0][0] (u0 == 1).
    const float w00 = kern[15];
    const float v0 = kern[15], v1 = kern[14], v2 = kern[13], v3 = kern[12];
    const float u1 = kern[11] / w00;
    const float u2 = kern[7]  / w00;
    const float u3 = kern[3]  / w00;

    const float* base  = x   + (size_t)bc * (HH * WW);
    float*       obase = out + (size_t)bc * (HH * WW);

    const bool l0  = (lane == 0);
    const bool l63 = (lane == 63);

    // Raw row load (zeros for out-of-image rows; wave-uniform branch).
    auto ldrow = [&](int r) -> float4 {
        if (r < 0 || r >= HH) return make_float4(0.f, 0.f, 0.f, 0.f);
        return *(const float4*)(base + r * WW + col0);
    };

    // Horizontal 4-tap blur over this lane's 4 output cols. Halo values come
    // from neighbor lanes' registers via shuffle; the wave spans the full
    // row, so lane-0 left / lane-63 right halos are zeros. Zero input rows
    // yield zero output rows with no branching needed.
    auto hblur = [&](float4 m) -> float4 {
        float xm2 = __shfl_up(m.z, 1);         // x[col0-2]
        float xm1 = __shfl_up(m.w, 1);         // x[col0-1]
        float x4  = __shfl_down(m.x, 1);       // x[col0+4]
        if (l0)  { xm2 = 0.f; xm1 = 0.f; }
        if (l63) { x4 = 0.f; }
        float4 h;
        h.x = v0*xm2 + v1*xm1 + v2*m.x + v3*m.y;
        h.y = v0*xm1 + v1*m.x + v2*m.y + v3*m.z;
        h.z = v0*m.x + v1*m.y + v2*m.z + v3*m.w;
        h.w = v0*m.y + v1*m.z + v2*m.w + v3*x4;
        return h;
    };

    // Prologue: 3 independent loads in flight before any compute.
    float4 m0 = ldrow(row0 - 2);
    float4 m1 = ldrow(row0 - 1);
    float4 m2 = ldrow(row0);
    float4 h0 = hblur(m0);
    float4 h1 = hblur(m1);
    float4 h2 = hblur(m2);

    // Rolling window, 2 rows/iter:
    //   out[r]   = H[r-2] + u1*H[r-1] + u2*H[r]   + u3*H[r+1]   (u0 == 1)
    //   out[r+1] = H[r-1] + u1*H[r]   + u2*H[r+1] + u3*H[r+2]
    #pragma unroll
    for (int k = 0; k < RPW; k += 2) {
        // Both loads issue before the dependent shuffle/FMA chain.
        const float4 m3 = ldrow(row0 + 1 + k);
        const float4 m4 = ldrow(row0 + 2 + k);
        const float4 h3 = hblur(m3);
        const float4 h4 = hblur(m4);

        f32x4 oa, ob;
        oa.x = h0.x + u1*h1.x + u2*h2.x + u3*h3.x;
        oa.y = h0.y + u1*h1.y + u2*h2.y + u3*h3.y;
        oa.z = h0.z + u1*h1.z + u2*h2.z + u3*h3.z;
        oa.w = h0.w + u1*h1.w + u2*h2.w + u3*h3.w;

        ob.x = h1.x + u1*h2.x + u2*h3.x + u3*h4.x;
        ob.y = h1.y + u1*h2.y + u2*h3.y + u3*h4.y;
        ob.z = h1.z + u1*h2.z + u2*h3.z + u3*h4.z;
        ob.w = h1.w + u1*h2.w + u2*h3.w + u3*h4.w;

        __builtin_nontemporal_store(oa, (f32x4*)(obase + (size_t)(row0 + k) * WW + col0));
        __builtin_nontemporal_store(ob, (f32x4*)(obase + (size_t)(row0 + k + 1) * WW + col0));

        h0 = h2; h1 = h3; h2 = h4;
    }
}

extern "C" void kernel_launch(void* const* d_in, const int* in_sizes, int n_in,
                              void* d_out, int out_size, void* d_ws, size_t ws_size,
                              hipStream_t stream) {
    const float* x    = (const float*)d_in[0];
    const float* kern = (const float*)d_in[1];
    float*       out  = (float*)d_out;
    const dim3 grid(BB * CC * (HH / 64)); // 4096 blocks (4 waves x 16 rows each)
    const dim3 block(256);
    blur_kernel<<<grid, block, 0, stream>>>(x, kern, out);
}

// Round 2
// 440.020 us; speedup vs baseline: 1.0194x; 1.0194x over previous
//
#include <hip/hip_runtime.h>

// Blur_1803886264378: depthwise 4x4 upfirdn2d blur, fp32.
// B=8, C=128, H=W=256, pad=(2,1) both dims -> same-size output.
// Separable (rank-1 [1,3,3,1] x [1,3,3,1]) blur fused in one kernel.
//
// R4 changes vs R2 (R3's pair-row + NT stores regressed -> reverted):
//  - Explicit one-row-lookahead prefetch: the row consumed by hblur() at
//    iteration k was loaded at iteration k-1, so each iteration's
//    global_load issues before the lgkmcnt-dependent shuffle chain of the
//    previous row. Single change vs the proven R2 schedule.
//  - Plain float4 stores (NT stores were a suspect in the R3 regression).

#define BB 8
#define CC 128
#define HH 256
#define WW 256
#define RPW 16   // rows per wave

__global__ __launch_bounds__(256) void blur_kernel(
    const float* __restrict__ x, const float* __restrict__ kern,
    float* __restrict__ out)
{
    const int lane  = threadIdx.x & 63;
    const int wv    = threadIdx.x >> 6;
    const int strip = blockIdx.x & 3;       // 4 block-strips of 64 rows
    const int bc    = blockIdx.x >> 2;

    const int row0 = strip * 64 + wv * RPW; // first output row for this wave
    const int col0 = lane * 4;              // first output col for this lane

    // Flipped kernel: w[di][dj] = kern[(3-di)*4 + (3-dj)].
    // Rank-1: v[dj] = w[0][dj], u[di] = w[di][0]/w[0][0] (u0 == 1).
    const float w00 = kern[15];
    const float v0 = kern[15], v1 = kern[14], v2 = kern[13], v3 = kern[12];
    const float u1 = kern[11] / w00;
    const float u2 = kern[7]  / w00;
    const float u3 = kern[3]  / w00;

    const float* base  = x   + (size_t)bc * (HH * WW);
    float*       obase = out + (size_t)bc * (HH * WW);

    const bool l0  = (lane == 0);
    const bool l63 = (lane == 63);

    // Raw row load (zeros for out-of-image rows; wave-uniform branch).
    auto ldrow = [&](int r) -> float4 {
        if (r < 0 || r >= HH) return make_float4(0.f, 0.f, 0.f, 0.f);
        return *(const float4*)(base + r * WW + col0);
    };

    // Horizontal 4-tap blur over this lane's 4 output cols. Halo values come
    // from neighbor lanes' registers via shuffle; the wave spans the full
    // row, so lane-0 left / lane-63 right halos are zeros. Zero input rows
    // yield zero output rows with no branching needed.
    auto hblur = [&](float4 m) -> float4 {
        float xm2 = __shfl_up(m.z, 1);         // x[col0-2]
        float xm1 = __shfl_up(m.w, 1);         // x[col0-1]
        float x4  = __shfl_down(m.x, 1);       // x[col0+4]
        if (l0)  { xm2 = 0.f; xm1 = 0.f; }
        if (l63) { x4 = 0.f; }
        float4 h;
        h.x = v0*xm2 + v1*xm1 + v2*m.x + v3*m.y;
        h.y = v0*xm1 + v1*m.x + v2*m.y + v3*m.z;
        h.z = v0*m.x + v1*m.y + v2*m.z + v3*m.w;
        h.w = v0*m.y + v1*m.z + v2*m.w + v3*x4;
        return h;
    };

    // Prologue: 4 independent loads issued back-to-back before any shuffle.
    const float4 mA = ldrow(row0 - 2);
    const float4 mB = ldrow(row0 - 1);
    const float4 mC = ldrow(row0);
    float4 mNext    = ldrow(row0 + 1);   // one-row lookahead
    float4 h0 = hblur(mA);
    float4 h1 = hblur(mB);
    float4 h2 = hblur(mC);

    // Rolling window: out[r] = H[r-2] + u1*H[r-1] + u2*H[r] + u3*H[r+1]
    // (u0 == 1). The row feeding h3 was loaded one iteration earlier.
    #pragma unroll
    for (int k = 0; k < RPW; ++k) {
        const float4 mPre = ldrow(row0 + 2 + k);   // prefetch next row
        const float4 h3   = hblur(mNext);          // consume prefetched row
        float4 o;
        o.x = h0.x + u1*h1.x + u2*h2.x + u3*h3.x;
        o.y = h0.y + u1*h1.y + u2*h2.y + u3*h3.y;
        o.z = h0.z + u1*h1.z + u2*h2.z + u3*h3.z;
        o.w = h0.w + u1*h1.w + u2*h2.w + u3*h3.w;
        *(float4*)(obase + (size_t)(row0 + k) * WW + col0) = o;
        h0 = h1; h1 = h2; h2 = h3; mNext = mPre;
    }
}

extern "C" void kernel_launch(void* const* d_in, const int* in_sizes, int n_in,
                              void* d_out, int out_size, void* d_ws, size_t ws_size,
                              hipStream_t stream) {
    const float* x    = (const float*)d_in[0];
    const float* kern = (const float*)d_in[1];
    float*       out  = (float*)d_out;
    const dim3 grid(BB * CC * (HH / 64)); // 4096 blocks (4 waves x 16 rows each)
    const dim3 block(256);
    blur_kernel<<<grid, block, 0, stream>>>(x, kern, out);
}